// Round 23
// baseline (103.326 us; speedup 1.0000x reference)
//
#include <hip/hip_runtime.h>
#include <hip/hip_bf16.h>
#include <math.h>

#define BB 2
#define SS 4096
#define HH 768
#define NHEADS 12
#define MTOT (BB*SS)     // 8192
#define NQKV (3*HH)      // 2304

typedef _Float16 f16;
typedef __attribute__((ext_vector_type(8))) _Float16 f16x8;
typedef __attribute__((ext_vector_type(4))) _Float16 f16x4;
typedef __attribute__((ext_vector_type(4))) float f32x4;

__device__ __forceinline__ void gld_lds16(const void* g, void* l) {
  __builtin_amdgcn_global_load_lds(
      (const __attribute__((address_space(1))) unsigned int*)g,
      (__attribute__((address_space(3))) unsigned int*)l, 16, 0, 0);
}

// -------- merged prolog: f32->f16 converts + RoPE cos/sin table ----------
__global__ __launch_bounds__(256)
void prep_all(const float* __restrict__ hs, const float* __restrict__ wq,
              const float* __restrict__ wo, f16* __restrict__ hs16,
              f16* __restrict__ wq16, f16* __restrict__ wo16,
              float* __restrict__ ctab, float* __restrict__ stab) {
  const int n1 = MTOT * HH / 4, n2 = NQKV * HH / 4, n3 = HH * HH / 4;
  const int n4 = SS * 32;
  int i = blockIdx.x * 256 + threadIdx.x;
  if (i < n1 + n2 + n3) {
    const float* src;
    f16* dst;
    int j = i;
    if (i < n1) { src = hs; dst = hs16; }
    else if (i < n1 + n2) { src = wq; dst = wq16; j = i - n1; }
    else { src = wo; dst = wo16; j = i - n1 - n2; }
    float4 v = reinterpret_cast<const float4*>(src)[j];
    f16x4 o;
    o[0] = (f16)v.x; o[1] = (f16)v.y; o[2] = (f16)v.z; o[3] = (f16)v.w;
    reinterpret_cast<f16x4*>(dst)[j] = o;
  } else if (i < n1 + n2 + n3 + n4) {
    int idx = i - n1 - n2 - n3;
    int s = idx >> 5;
    int j = idx & 31;
    const double r = 0.7498942093324559;  // 10000^(-1/32)
    double inv = 1.0;
    for (int t = 0; t < j; ++t) inv *= r;
    double ph = (double)s * inv;
    const double TWO_PI = 6.283185307179586;
    double red = ph - TWO_PI * floor(ph / TWO_PI);
    float rf = (float)red;
    ctab[idx] = cosf(rf);
    stab[idx] = sinf(rf);
  }
}

// ======== GEMM1: 128x128 tile, 8 waves (4Mx2N), BK=32, 3-buf counted =====
// R20 winner, verbatim. Fused RoPE/scale epilogue -> q/k/v f16.
__global__ __launch_bounds__(512)
void gemm1_f16(const f16* __restrict__ A, const f16* __restrict__ Bw,
               f16* __restrict__ Oq, f16* __restrict__ Ok, f16* __restrict__ Ov,
               const int* __restrict__ pos,
               const float* __restrict__ ctab, const float* __restrict__ stab) {
  __shared__ __align__(16) f16 As[3][128][32];   // 24 KB
  __shared__ __align__(16) f16 Bs[3][128][32];   // 24 KB
  const int K = HH;
  const int tid = threadIdx.x;         // 0..511
  const int lane = tid & 63;
  const int w = tid >> 6;              // 0..7
  const int wr = w & 3;                // row-wave: 32 rows
  const int wc = w >> 2;               // col-wave: 64 cols (one head)

  // M-chunked XCD map: grid 1152 = 8 xcd * (8 mch * 18 ntile)
  const int bid = blockIdx.x;
  const int xcd = bid & 7;
  const int idx = bid >> 3;
  const int bm = (xcd * 8 + (idx & 7)) * 128;
  const int bn = (idx >> 3) * 128;

  f32x4 acc[2][4] = {};

  const int rA = tid >> 2;             // staging row 0..127
  const int cA = tid & 3;              // staging chunk 0..3
  const int gsw = (cA ^ ((rA >> 1) & 3)) * 8;
  const int fr = lane & 15;
  const int pc = (((lane >> 4) ^ ((fr >> 1) & 3)) * 8);

  auto stage = [&](int buf, int k0) {
    gld_lds16(A + (size_t)(bm + rA) * K + k0 + gsw,
              (char*)&As[0][0][0] + buf * 8192 + tid * 16);
    gld_lds16(Bw + (size_t)(bn + rA) * K + k0 + gsw,
              (char*)&Bs[0][0][0] + buf * 8192 + tid * 16);
  };
  auto compute = [&](int buf) {
    f16x8 av[2], bv[4];
#pragma unroll
    for (int m = 0; m < 2; ++m)
      av[m] = *reinterpret_cast<const f16x8*>(&As[buf][wr * 32 + m * 16 + fr][pc]);
#pragma unroll
    for (int n = 0; n < 4; ++n)
      bv[n] = *reinterpret_cast<const f16x8*>(&Bs[buf][wc * 64 + n * 16 + fr][pc]);
    __builtin_amdgcn_s_setprio(1);
#pragma unroll
    for (int m = 0; m < 2; ++m)
#pragma unroll
      for (int n = 0; n < 4; ++n)
        acc[m][n] = __builtin_amdgcn_mfma_f32_16x16x32_f16(av[m], bv[n],
                                                           acc[m][n], 0, 0, 0);
    __builtin_amdgcn_s_setprio(0);
  };

  const int T = K >> 5;   // 24
  stage(0, 0);
  stage(1, 32);
  for (int t = 0; t < T; ++t) {
    if (t == T - 1)
      asm volatile("s_waitcnt vmcnt(0)" ::: "memory");
    else
      asm volatile("s_waitcnt vmcnt(2)" ::: "memory");
    __builtin_amdgcn_s_barrier();
    __builtin_amdgcn_sched_barrier(0);
    if (t + 2 < T) stage((t + 2) % 3, (t + 2) << 5);
    compute(t % 3);
  }

  const int cl = lane & 15;
  const int rg = lane >> 4;
  const int sec = bn / HH;             // 0=q 1=k 2=v (uniform per block)
  f16* dst = (sec == 0) ? Oq : ((sec == 1) ? Ok : Ov);
  const int hb = bn - sec * HH + wc * 64;
#pragma unroll
  for (int m = 0; m < 2; ++m)
#pragma unroll
    for (int r = 0; r < 4; ++r) {
      const int row = bm + wr * 32 + m * 16 + rg * 4 + r;
      if (sec < 2) {
        const int sp = pos[row];
#pragma unroll
        for (int n = 0; n < 4; ++n) {
          const int hd = hb + n * 16 + cl;
          const int d = hd & 63;
          const int d2 = d & 31;
          const float c = ctab[sp * 32 + d2];
          const float sn = stab[sp * 32 + d2];
          float val = acc[m][n][r];
          const float pv = acc[m][n ^ 2][r];
          val = (d < 32) ? (val * c - pv * sn) : (val * c + pv * sn);
          if (sec == 0) val *= 0.125f;
          dst[(size_t)row * HH + hd] = (f16)val;
        }
      } else {
#pragma unroll
        for (int n = 0; n < 4; ++n)
          dst[(size_t)row * HH + hb + n * 16 + cl] = (f16)acc[m][n][r];
      }
    }
}

// ======== GEMM2: 64x64 tile, 4 waves (2x2), BK=32, 3-buf counted =========
// Occupancy-matched: grid 1536 = 6 blocks/CU exactly (zero tail), 24 waves.
// LDS 24 KB; 1 A + 1 B gld_lds per thread per stage; vmcnt(2) counted ring.
// Same involution swizzle + M-chunked XCD map (16 M-tiles/XCD, 1 MB panel).
__global__ __launch_bounds__(256)
void gemm2_64(const f16* __restrict__ A, const f16* __restrict__ Bw,
              float* __restrict__ C) {
  __shared__ __align__(16) f16 As[3][64][32];   // 12 KB
  __shared__ __align__(16) f16 Bs[3][64][32];   // 12 KB
  const int K = HH, NN = HH;
  const int tid = threadIdx.x;         // 0..255
  const int lane = tid & 63;
  const int w = tid >> 6;              // 0..3
  const int wr = w & 1;                // 2x2 wave grid, 32x32 per wave
  const int wc = w >> 1;

  // grid 1536 = 8 xcd * 192; Mtiles = 128 -> 16 per XCD chunk
  const int bid = blockIdx.x;
  const int xcd = bid & 7;
  const int idx = bid >> 3;            // 0..191
  const int bm = (xcd * 16 + (idx & 15)) * 64;
  const int bn = (idx >> 4) * 64;      // 12 N-tiles

  f32x4 acc[2][2] = {};

  const int srow = tid >> 2;           // staging row 0..63
  const int sch = tid & 3;
  const int gsw = (sch ^ ((srow >> 1) & 3)) * 8;
  const int fr = lane & 15;
  const int pc = (((lane >> 4) ^ ((fr >> 1) & 3)) * 8);

  auto stage = [&](int buf, int k0) {
    gld_lds16(A + (size_t)(bm + srow) * K + k0 + gsw,
              (char*)&As[0][0][0] + buf * 4096 + tid * 16);
    gld_lds16(Bw + (size_t)(bn + srow) * K + k0 + gsw,
              (char*)&Bs[0][0][0] + buf * 4096 + tid * 16);
  };
  auto compute = [&](int buf) {
    f16x8 av[2], bv[2];
#pragma unroll
    for (int m = 0; m < 2; ++m)
      av[m] = *reinterpret_cast<const f16x8*>(&As[buf][wr * 32 + m * 16 + fr][pc]);
#pragma unroll
    for (int n = 0; n < 2; ++n)
      bv[n] = *reinterpret_cast<const f16x8*>(&Bs[buf][wc * 32 + n * 16 + fr][pc]);
    __builtin_amdgcn_s_setprio(1);
#pragma unroll
    for (int m = 0; m < 2; ++m)
#pragma unroll
      for (int n = 0; n < 2; ++n)
        acc[m][n] = __builtin_amdgcn_mfma_f32_16x16x32_f16(av[m], bv[n],
                                                           acc[m][n], 0, 0, 0);
    __builtin_amdgcn_s_setprio(0);
  };

  const int T = K >> 5;   // 24
  stage(0, 0);
  stage(1, 32);
  for (int t = 0; t < T; ++t) {
    if (t == T - 1)
      asm volatile("s_waitcnt vmcnt(0)" ::: "memory");
    else
      asm volatile("s_waitcnt vmcnt(2)" ::: "memory");
    __builtin_amdgcn_s_barrier();
    __builtin_amdgcn_sched_barrier(0);
    if (t + 2 < T) stage((t + 2) % 3, (t + 2) << 5);
    compute(t % 3);
  }

  const int cl = lane & 15;
  const int rg = lane >> 4;
#pragma unroll
  for (int m = 0; m < 2; ++m)
#pragma unroll
    for (int n = 0; n < 2; ++n)
#pragma unroll
      for (int r = 0; r < 4; ++r) {
        int row = bm + wr * 32 + m * 16 + rg * 4 + r;
        int col = bn + wc * 32 + n * 16 + cl;
        C[(size_t)row * NN + col] = acc[m][n][r];
      }
}

// ---------------- MFMA sliding-window attention (R14, verbatim) ----------
#define AQT 64
#define AKT 192
#define KP 72     // K row pad (f16): 144 B rows
#define VPP 200   // P row stride (f16) inside Ks region

__global__ __launch_bounds__(256)
void attn_kernel(const f16* __restrict__ qg, const f16* __restrict__ kg,
                 const f16* __restrict__ vg, f16* __restrict__ og) {
  __shared__ __align__(16) f16 Ks[AKT][KP];     // 27648 B, reused for P[64][VPP]
  __shared__ __align__(16) f16 Vs[64][192];     // 24576 B (transposed V, swizzled)
  __shared__ float sums[AQT];

  const int tid = threadIdx.x;
  const int lane = tid & 63;
  const int wq = tid >> 6;
  const int l15 = lane & 15, g = lane >> 4;
  const int lin = (blockIdx.x & 7) * 192 + (blockIdx.x >> 3);
  const int qt = lin & 63;
  const int h = (lin >> 6) % NHEADS;
  const int b = lin / (64 * NHEADS);
  const int q0 = qt * AQT;
  const int kbase = q0 - 64;

  const size_t qrow = ((size_t)(b * SS + q0 + wq * 16 + l15)) * HH + h * 64;
  const f16x8 bq0 = *reinterpret_cast<const f16x8*>(&qg[qrow + g * 8]);
  const f16x8 bq1 = *reinterpret_cast<const f16x8*>(&qg[qrow + 32 + g * 8]);

#pragma unroll
  for (int i = 0; i < 6; ++i) {
    int idx = tid + i * 256;
    int r = idx >> 3, ch = idx & 7;
    int kglob = kbase + r;
    f16x8 v = {};
    if (kglob >= 0 && kglob < SS)
      v = *reinterpret_cast<const f16x8*>(
          &kg[((size_t)(b * SS + kglob)) * HH + h * 64 + ch * 8]);
    *reinterpret_cast<f16x8*>(&Ks[r][ch * 8]) = v;
  }
#pragma unroll
  for (int i = 0; i < 6; ++i) {
    int idx = tid + i * 256;
    int r = idx >> 3, ch = idx & 7;
    int kglob = kbase + r;
    f16x8 v = {};
    if (kglob >= 0 && kglob < SS)
      v = *reinterpret_cast<const f16x8*>(
          &vg[((size_t)(b * SS + kglob)) * HH + h * 64 + ch * 8]);
    const int c = r >> 3, o = r & 7;
#pragma unroll
    for (int j = 0; j < 8; ++j) {
      const int row = ch * 8 + j;
      const int cp = c ^ (row & 7) ^ ((row >> 3) & 7);
      Vs[row][cp * 8 + o] = v[j];
    }
  }
  __syncthreads();

  f32x4 accs[12] = {};
#pragma unroll
  for (int f = 0; f < 12; ++f) {
    f16x8 ak = *reinterpret_cast<const f16x8*>(&Ks[f * 16 + l15][g * 8]);
    accs[f] = __builtin_amdgcn_mfma_f32_16x16x32_f16(ak, bq0, accs[f], 0, 0, 0);
  }
#pragma unroll
  for (int f = 0; f < 12; ++f) {
    f16x8 ak = *reinterpret_cast<const f16x8*>(&Ks[f * 16 + l15][32 + g * 8]);
    accs[f] = __builtin_amdgcn_mfma_f32_16x16x32_f16(ak, bq1, accs[f], 0, 0, 0);
  }
  __syncthreads();   // Ks becomes P storage

  const int qloc = wq * 16 + l15;
  float mx = -1e30f;
#pragma unroll
  for (int f = 0; f < 12; ++f)
#pragma unroll
    for (int r = 0; r < 4; ++r) {
      int key = f * 16 + g * 4 + r;
      int kglob = kbase + key;
      bool valid = (key >= qloc) && (key <= qloc + 128) && (kglob >= 0) && (kglob < SS);
      float s = valid ? accs[f][r] : -1e30f;
      accs[f][r] = s;
      mx = fmaxf(mx, s);
    }
  mx = fmaxf(mx, __shfl_xor(mx, 16));
  mx = fmaxf(mx, __shfl_xor(mx, 32));
  f16* Ps = &Ks[0][0];
  float sum = 0.f;
#pragma unroll
  for (int f = 0; f < 12; ++f) {
    float p0 = __expf(accs[f][0] - mx);
    float p1 = __expf(accs[f][1] - mx);
    float p2 = __expf(accs[f][2] - mx);
    float p3 = __expf(accs[f][3] - mx);
    sum += (p0 + p1) + (p2 + p3);
    f16x4 pk;
    pk[0] = (f16)p0; pk[1] = (f16)p1; pk[2] = (f16)p2; pk[3] = (f16)p3;
    *reinterpret_cast<f16x4*>(&Ps[(size_t)qloc * VPP + f * 16 + g * 4]) = pk;
  }
  sum += __shfl_xor(sum, 16);
  sum += __shfl_xor(sum, 32);
  if (g == 0) sums[qloc] = sum;

  f32x4 acco[4] = {};
#pragma unroll
  for (int ks = 0; ks < 6; ++ks) {
    f16x8 pa = *reinterpret_cast<const f16x8*>(&Ps[(size_t)(wq * 16 + l15) * VPP + ks * 32 + g * 8]);
#pragma unroll
    for (int n = 0; n < 4; ++n) {
      const int row = n * 16 + l15;
      const int cp = (4 * ks + g) ^ (row & 7) ^ ((row >> 3) & 7);
      f16x8 bv = *reinterpret_cast<const f16x8*>(&Vs[row][cp * 8]);
      acco[n] = __builtin_amdgcn_mfma_f32_16x16x32_f16(pa, bv, acco[n], 0, 0, 0);
    }
  }
#pragma unroll
  for (int r = 0; r < 4; ++r) {
    int qo = wq * 16 + g * 4 + r;
    float inv = 1.0f / sums[qo];
    size_t base = ((size_t)(b * SS + q0 + qo)) * HH + h * 64;
#pragma unroll
    for (int n = 0; n < 4; ++n)
      og[base + n * 16 + l15] = (f16)(acco[n][r] * inv);
  }
}

extern "C" void kernel_launch(void* const* d_in, const int* in_sizes, int n_in,
                              void* d_out, int out_size, void* d_ws, size_t ws_size,
                              hipStream_t stream) {
  const float* hs = (const float*)d_in[0];
  const int* pos = (const int*)d_in[3];
  const float* Wqkv = (const float*)d_in[4];
  const float* Wo = (const float*)d_in[5];
  float* out = (float*)d_out;

  uint8_t* ws = (uint8_t*)d_ws;
  size_t off = 0;
  float* ctab = (float*)(ws + off); off += (size_t)SS * 32 * 4;
  float* stab = (float*)(ws + off); off += (size_t)SS * 32 * 4;
  f16* hs16 = (f16*)(ws + off); off += (size_t)MTOT * HH * 2;
  f16* wq16 = (f16*)(ws + off); off += (size_t)NQKV * HH * 2;
  f16* wo16 = (f16*)(ws + off); off += (size_t)HH * HH * 2;
  f16* qf = (f16*)(ws + off); off += (size_t)MTOT * HH * 2;
  f16* kf = (f16*)(ws + off); off += (size_t)MTOT * HH * 2;
  f16* vf = (f16*)(ws + off); off += (size_t)MTOT * HH * 2;
  f16* af = (f16*)(ws + off); off += (size_t)MTOT * HH * 2;

  const int nprep = (MTOT * HH + NQKV * HH + HH * HH) / 4 + SS * 32;
  prep_all<<<(nprep + 255) / 256, 256, 0, stream>>>(hs, Wqkv, Wo, hs16, wq16,
                                                    wo16, ctab, stab);

  // 1. QKV projection + fused RoPE/scale (128x128, 8 waves, 3-buf counted)
  gemm1_f16<<<(MTOT / 128) * (NQKV / 128), 512, 0, stream>>>(
      hs16, wq16, qf, kf, vf, pos, ctab, stab);
  // 2. Attention
  attn_kernel<<<BB * NHEADS * (SS / AQT), 256, 0, stream>>>(qf, kf, vf, af);
  // 3. Output projection (64x64, 4 waves, grid 1536 = 6 blocks/CU exact)
  gemm2_64<<<(MTOT / 64) * (HH / 64), 256, 0, stream>>>(af, wo16, out);
}

// Round 24
// 99.126 us; speedup vs baseline: 1.0424x; 1.0424x over previous
//
#include <hip/hip_runtime.h>
#include <hip/hip_bf16.h>
#include <math.h>

#define BB 2
#define SS 4096
#define HH 768
#define NHEADS 12
#define MTOT (BB*SS)     // 8192
#define NQKV (3*HH)      // 2304

typedef _Float16 f16;
typedef __attribute__((ext_vector_type(8))) _Float16 f16x8;
typedef __attribute__((ext_vector_type(4))) _Float16 f16x4;
typedef __attribute__((ext_vector_type(4))) float f32x4;

__device__ __forceinline__ void gld_lds16(const void* g, void* l) {
  __builtin_amdgcn_global_load_lds(
      (const __attribute__((address_space(1))) unsigned int*)g,
      (__attribute__((address_space(3))) unsigned int*)l, 16, 0, 0);
}

// -------- merged prolog: f32->f16 converts + RoPE cos/sin table ----------
__global__ __launch_bounds__(256)
void prep_all(const float* __restrict__ hs, const float* __restrict__ wq,
              const float* __restrict__ wo, f16* __restrict__ hs16,
              f16* __restrict__ wq16, f16* __restrict__ wo16,
              float* __restrict__ ctab, float* __restrict__ stab) {
  const int n1 = MTOT * HH / 4, n2 = NQKV * HH / 4, n3 = HH * HH / 4;
  const int n4 = SS * 32;
  int i = blockIdx.x * 256 + threadIdx.x;
  if (i < n1 + n2 + n3) {
    const float* src;
    f16* dst;
    int j = i;
    if (i < n1) { src = hs; dst = hs16; }
    else if (i < n1 + n2) { src = wq; dst = wq16; j = i - n1; }
    else { src = wo; dst = wo16; j = i - n1 - n2; }
    float4 v = reinterpret_cast<const float4*>(src)[j];
    f16x4 o;
    o[0] = (f16)v.x; o[1] = (f16)v.y; o[2] = (f16)v.z; o[3] = (f16)v.w;
    reinterpret_cast<f16x4*>(dst)[j] = o;
  } else if (i < n1 + n2 + n3 + n4) {
    int idx = i - n1 - n2 - n3;
    int s = idx >> 5;
    int j = idx & 31;
    const double r = 0.7498942093324559;  // 10000^(-1/32)
    double inv = 1.0;
    for (int t = 0; t < j; ++t) inv *= r;
    double ph = (double)s * inv;
    const double TWO_PI = 6.283185307179586;
    double red = ph - TWO_PI * floor(ph / TWO_PI);
    float rf = (float)red;
    ctab[idx] = cosf(rf);
    stab[idx] = sinf(rf);
  }
}

// ======== GEMM: 128x128 tile, 8 waves (4Mx2N), BK=32, 3-buf counted ======
// R19 geometry (max waves/CU) + R10 counted-vmcnt ring: stage t+2 issued
// after the barrier; vmcnt(2) waits only stage t (t+1's 2 loads fly on).
// 48 KB LDS -> 3 blocks/CU = 24 waves. Involution chunk swizzle +
// M-chunked XCD map verified R9/R10. EPI=1: RoPE -> q/k/v. EPI=0: f32 C.
template<int EPI, int NN>
__global__ __launch_bounds__(512)
void gemm_128x8w(const f16* __restrict__ A, const f16* __restrict__ Bw,
                 float* __restrict__ C,
                 f16* __restrict__ Oq, f16* __restrict__ Ok, f16* __restrict__ Ov,
                 const int* __restrict__ pos,
                 const float* __restrict__ ctab, const float* __restrict__ stab) {
  __shared__ __align__(16) f16 As[3][128][32];   // 24 KB
  __shared__ __align__(16) f16 Bs[3][128][32];   // 24 KB
  const int K = HH;
  const int tid = threadIdx.x;         // 0..511
  const int lane = tid & 63;
  const int w = tid >> 6;              // 0..7
  const int wr = w & 3;                // row-wave: 32 rows
  const int wc = w >> 2;               // col-wave: 64 cols (one head)

  // M-chunked XCD map: grid = 8 xcd * (8 mch * NN/128)
  const int bid = blockIdx.x;
  const int xcd = bid & 7;
  const int idx = bid >> 3;
  const int bm = (xcd * 8 + (idx & 7)) * 128;
  const int bn = (idx >> 3) * 128;

  f32x4 acc[2][4] = {};

  const int rA = tid >> 2;             // staging row 0..127
  const int cA = tid & 3;              // staging chunk 0..3
  const int gsw = (cA ^ ((rA >> 1) & 3)) * 8;
  const int fr = lane & 15;
  const int pc = (((lane >> 4) ^ ((fr >> 1) & 3)) * 8);

  // stage: 1 A-load + 1 B-load per thread
  auto stage = [&](int buf, int k0) {
    gld_lds16(A + (size_t)(bm + rA) * K + k0 + gsw,
              (char*)&As[0][0][0] + buf * 8192 + tid * 16);
    gld_lds16(Bw + (size_t)(bn + rA) * K + k0 + gsw,
              (char*)&Bs[0][0][0] + buf * 8192 + tid * 16);
  };
  auto compute = [&](int buf) {
    f16x8 av[2], bv[4];
#pragma unroll
    for (int m = 0; m < 2; ++m)
      av[m] = *reinterpret_cast<const f16x8*>(&As[buf][wr * 32 + m * 16 + fr][pc]);
#pragma unroll
    for (int n = 0; n < 4; ++n)
      bv[n] = *reinterpret_cast<const f16x8*>(&Bs[buf][wc * 64 + n * 16 + fr][pc]);
    __builtin_amdgcn_s_setprio(1);
#pragma unroll
    for (int m = 0; m < 2; ++m)
#pragma unroll
      for (int n = 0; n < 4; ++n)
        acc[m][n] = __builtin_amdgcn_mfma_f32_16x16x32_f16(av[m], bv[n],
                                                           acc[m][n], 0, 0, 0);
    __builtin_amdgcn_s_setprio(0);
  };

  const int T = K >> 5;   // 24
  stage(0, 0);
  stage(1, 32);
  for (int t = 0; t < T; ++t) {
    // wait for stage t only; stage t+1's 2 loads stay in flight
    if (t == T - 1)
      asm volatile("s_waitcnt vmcnt(0)" ::: "memory");
    else
      asm volatile("s_waitcnt vmcnt(2)" ::: "memory");
    __builtin_amdgcn_s_barrier();      // certifies reads of buf[(t+2)%3] done
    __builtin_amdgcn_sched_barrier(0);
    if (t + 2 < T) stage((t + 2) % 3, (t + 2) << 5);
    compute(t % 3);
  }

  const int cl = lane & 15;
  const int rg = lane >> 4;
  if (EPI == 0) {
#pragma unroll
    for (int m = 0; m < 2; ++m)
#pragma unroll
      for (int n = 0; n < 4; ++n)
#pragma unroll
        for (int r = 0; r < 4; ++r) {
          int row = bm + wr * 32 + m * 16 + rg * 4 + r;
          int col = bn + wc * 64 + n * 16 + cl;
          C[(size_t)row * NN + col] = acc[m][n][r];
        }
  } else {
    const int sec = bn / HH;             // 0=q 1=k 2=v (uniform per block)
    f16* dst = (sec == 0) ? Oq : ((sec == 1) ? Ok : Ov);
    const int hb = bn - sec * HH + wc * 64;
#pragma unroll
    for (int m = 0; m < 2; ++m)
#pragma unroll
      for (int r = 0; r < 4; ++r) {
        const int row = bm + wr * 32 + m * 16 + rg * 4 + r;
        if (sec < 2) {
          const int sp = pos[row];
#pragma unroll
          for (int n = 0; n < 4; ++n) {
            const int hd = hb + n * 16 + cl;
            const int d = hd & 63;
            const int d2 = d & 31;
            const float c = ctab[sp * 32 + d2];
            const float sn = stab[sp * 32 + d2];
            float val = acc[m][n][r];
            const float pv = acc[m][n ^ 2][r];
            val = (d < 32) ? (val * c - pv * sn) : (val * c + pv * sn);
            if (sec == 0) val *= 0.125f;
            dst[(size_t)row * HH + hd] = (f16)val;
          }
        } else {
#pragma unroll
          for (int n = 0; n < 4; ++n)
            dst[(size_t)row * HH + hb + n * 16 + cl] = (f16)acc[m][n][r];
        }
      }
  }
}

// ---------------- MFMA sliding-window attention (R14, verbatim) ----------
#define AQT 64
#define AKT 192
#define KP 72     // K row pad (f16): 144 B rows
#define VPP 200   // P row stride (f16) inside Ks region

__global__ __launch_bounds__(256)
void attn_kernel(const f16* __restrict__ qg, const f16* __restrict__ kg,
                 const f16* __restrict__ vg, f16* __restrict__ og) {
  __shared__ __align__(16) f16 Ks[AKT][KP];     // 27648 B, reused for P[64][VPP]
  __shared__ __align__(16) f16 Vs[64][192];     // 24576 B (transposed V, swizzled)
  __shared__ float sums[AQT];

  const int tid = threadIdx.x;
  const int lane = tid & 63;
  const int wq = tid >> 6;
  const int l15 = lane & 15, g = lane >> 4;
  const int lin = (blockIdx.x & 7) * 192 + (blockIdx.x >> 3);
  const int qt = lin & 63;
  const int h = (lin >> 6) % NHEADS;
  const int b = lin / (64 * NHEADS);
  const int q0 = qt * AQT;
  const int kbase = q0 - 64;

  const size_t qrow = ((size_t)(b * SS + q0 + wq * 16 + l15)) * HH + h * 64;
  const f16x8 bq0 = *reinterpret_cast<const f16x8*>(&qg[qrow + g * 8]);
  const f16x8 bq1 = *reinterpret_cast<const f16x8*>(&qg[qrow + 32 + g * 8]);

#pragma unroll
  for (int i = 0; i < 6; ++i) {
    int idx = tid + i * 256;
    int r = idx >> 3, ch = idx & 7;
    int kglob = kbase + r;
    f16x8 v = {};
    if (kglob >= 0 && kglob < SS)
      v = *reinterpret_cast<const f16x8*>(
          &kg[((size_t)(b * SS + kglob)) * HH + h * 64 + ch * 8]);
    *reinterpret_cast<f16x8*>(&Ks[r][ch * 8]) = v;
  }
#pragma unroll
  for (int i = 0; i < 6; ++i) {
    int idx = tid + i * 256;
    int r = idx >> 3, ch = idx & 7;
    int kglob = kbase + r;
    f16x8 v = {};
    if (kglob >= 0 && kglob < SS)
      v = *reinterpret_cast<const f16x8*>(
          &vg[((size_t)(b * SS + kglob)) * HH + h * 64 + ch * 8]);
    const int c = r >> 3, o = r & 7;
#pragma unroll
    for (int j = 0; j < 8; ++j) {
      const int row = ch * 8 + j;
      const int cp = c ^ (row & 7) ^ ((row >> 3) & 7);
      Vs[row][cp * 8 + o] = v[j];
    }
  }
  __syncthreads();

  f32x4 accs[12] = {};
#pragma unroll
  for (int f = 0; f < 12; ++f) {
    f16x8 ak = *reinterpret_cast<const f16x8*>(&Ks[f * 16 + l15][g * 8]);
    accs[f] = __builtin_amdgcn_mfma_f32_16x16x32_f16(ak, bq0, accs[f], 0, 0, 0);
  }
#pragma unroll
  for (int f = 0; f < 12; ++f) {
    f16x8 ak = *reinterpret_cast<const f16x8*>(&Ks[f * 16 + l15][32 + g * 8]);
    accs[f] = __builtin_amdgcn_mfma_f32_16x16x32_f16(ak, bq1, accs[f], 0, 0, 0);
  }
  __syncthreads();   // Ks becomes P storage

  const int qloc = wq * 16 + l15;
  float mx = -1e30f;
#pragma unroll
  for (int f = 0; f < 12; ++f)
#pragma unroll
    for (int r = 0; r < 4; ++r) {
      int key = f * 16 + g * 4 + r;
      int kglob = kbase + key;
      bool valid = (key >= qloc) && (key <= qloc + 128) && (kglob >= 0) && (kglob < SS);
      float s = valid ? accs[f][r] : -1e30f;
      accs[f][r] = s;
      mx = fmaxf(mx, s);
    }
  mx = fmaxf(mx, __shfl_xor(mx, 16));
  mx = fmaxf(mx, __shfl_xor(mx, 32));
  f16* Ps = &Ks[0][0];
  float sum = 0.f;
#pragma unroll
  for (int f = 0; f < 12; ++f) {
    float p0 = __expf(accs[f][0] - mx);
    float p1 = __expf(accs[f][1] - mx);
    float p2 = __expf(accs[f][2] - mx);
    float p3 = __expf(accs[f][3] - mx);
    sum += (p0 + p1) + (p2 + p3);
    f16x4 pk;
    pk[0] = (f16)p0; pk[1] = (f16)p1; pk[2] = (f16)p2; pk[3] = (f16)p3;
    *reinterpret_cast<f16x4*>(&Ps[(size_t)qloc * VPP + f * 16 + g * 4]) = pk;
  }
  sum += __shfl_xor(sum, 16);
  sum += __shfl_xor(sum, 32);
  if (g == 0) sums[qloc] = sum;

  f32x4 acco[4] = {};
#pragma unroll
  for (int ks = 0; ks < 6; ++ks) {
    f16x8 pa = *reinterpret_cast<const f16x8*>(&Ps[(size_t)(wq * 16 + l15) * VPP + ks * 32 + g * 8]);
#pragma unroll
    for (int n = 0; n < 4; ++n) {
      const int row = n * 16 + l15;
      const int cp = (4 * ks + g) ^ (row & 7) ^ ((row >> 3) & 7);
      f16x8 bv = *reinterpret_cast<const f16x8*>(&Vs[row][cp * 8]);
      acco[n] = __builtin_amdgcn_mfma_f32_16x16x32_f16(pa, bv, acco[n], 0, 0, 0);
    }
  }
#pragma unroll
  for (int r = 0; r < 4; ++r) {
    int qo = wq * 16 + g * 4 + r;
    float inv = 1.0f / sums[qo];
    size_t base = ((size_t)(b * SS + q0 + qo)) * HH + h * 64;
#pragma unroll
    for (int n = 0; n < 4; ++n)
      og[base + n * 16 + l15] = (f16)(acco[n][r] * inv);
  }
}

extern "C" void kernel_launch(void* const* d_in, const int* in_sizes, int n_in,
                              void* d_out, int out_size, void* d_ws, size_t ws_size,
                              hipStream_t stream) {
  const float* hs = (const float*)d_in[0];
  const int* pos = (const int*)d_in[3];
  const float* Wqkv = (const float*)d_in[4];
  const float* Wo = (const float*)d_in[5];
  float* out = (float*)d_out;

  uint8_t* ws = (uint8_t*)d_ws;
  size_t off = 0;
  float* ctab = (float*)(ws + off); off += (size_t)SS * 32 * 4;
  float* stab = (float*)(ws + off); off += (size_t)SS * 32 * 4;
  f16* hs16 = (f16*)(ws + off); off += (size_t)MTOT * HH * 2;
  f16* wq16 = (f16*)(ws + off); off += (size_t)NQKV * HH * 2;
  f16* wo16 = (f16*)(ws + off); off += (size_t)HH * HH * 2;
  f16* qf = (f16*)(ws + off); off += (size_t)MTOT * HH * 2;
  f16* kf = (f16*)(ws + off); off += (size_t)MTOT * HH * 2;
  f16* vf = (f16*)(ws + off); off += (size_t)MTOT * HH * 2;
  f16* af = (f16*)(ws + off); off += (size_t)MTOT * HH * 2;

  const int nprep = (MTOT * HH + NQKV * HH + HH * HH) / 4 + SS * 32;
  prep_all<<<(nprep + 255) / 256, 256, 0, stream>>>(hs, Wqkv, Wo, hs16, wq16,
                                                    wo16, ctab, stab);

  // 1. QKV projection + fused RoPE/scale (128x128, 8 waves, 3-buf counted)
  gemm_128x8w<1, NQKV><<<(MTOT / 128) * (NQKV / 128), 512, 0, stream>>>(
      hs16, wq16, nullptr, qf, kf, vf, pos, ctab, stab);
  // 2. Attention
  attn_kernel<<<BB * NHEADS * (SS / AQT), 256, 0, stream>>>(qf, kf, vf, af);
  // 3. Output projection (same template, f32 C, grid 384)
  gemm_128x8w<0, HH><<<(MTOT / 128) * (HH / 128), 512, 0, stream>>>(
      af, wo16, out, nullptr, nullptr, nullptr, nullptr, nullptr, nullptr);
}